// Round 4
// baseline (755.132 us; speedup 1.0000x reference)
//
#include <hip/hip_runtime.h>
#include <hip/hip_bf16.h>
#include <stdint.h>

#define T_TOK 4096
#define DM 1024
#define DF 4096
#define NE 8
#define PADROWS 10240   // 8192 + 8*256 (offsets padded to 256-row granularity)

typedef __attribute__((ext_vector_type(8))) short short8;
typedef __attribute__((ext_vector_type(8))) unsigned short ushort8_t;  // 16 B
typedef __attribute__((ext_vector_type(4))) float f32x4;

__device__ __forceinline__ unsigned short f2bf(float f) {
    union { float f; unsigned u; } v; v.f = f;
    unsigned r = v.u + 0x7fffu + ((v.u >> 16) & 1u);   // RNE
    return (unsigned short)(r >> 16);
}

__device__ __forceinline__ void async_cp16(const void* g, void* l) {
    __builtin_amdgcn_global_load_lds(
        (const __attribute__((address_space(1))) unsigned*)g,
        (__attribute__((address_space(3))) unsigned*)l,
        16, 0, 0);
}

// ---------------- router: fp32 logits, top-2, softmax ----------------
__global__ __launch_bounds__(256) void k_router(
    const float* __restrict__ x, const float* __restrict__ rw,
    const float* __restrict__ rb, int* __restrict__ counts,
    int* __restrict__ listTok, int4* __restrict__ tokRec,
    float2* __restrict__ tokGate)
{
    int l  = threadIdx.x & 63;
    int wv = threadIdx.x >> 6;
    int t  = blockIdx.x * 4 + wv;
    const float* xr = x + (size_t)t * DM;
    float acc[NE];
#pragma unroll
    for (int e = 0; e < NE; ++e) acc[e] = 0.f;
#pragma unroll
    for (int i = 0; i < 16; ++i) {
        int d = i * 64 + l;
        float xv = xr[d];
        const float4* wp = (const float4*)(rw + (size_t)d * NE);
        float4 w0 = wp[0], w1 = wp[1];
        acc[0] += xv * w0.x; acc[1] += xv * w0.y; acc[2] += xv * w0.z; acc[3] += xv * w0.w;
        acc[4] += xv * w1.x; acc[5] += xv * w1.y; acc[6] += xv * w1.z; acc[7] += xv * w1.w;
    }
#pragma unroll
    for (int off = 32; off >= 1; off >>= 1)
#pragma unroll
        for (int e = 0; e < NE; ++e) acc[e] += __shfl_down(acc[e], off);
    if (l == 0) {
        float lg[NE];
#pragma unroll
        for (int e = 0; e < NE; ++e) lg[e] = acc[e] + rb[e];
        int i1 = 0; float s1 = lg[0];
#pragma unroll
        for (int e = 1; e < NE; ++e) if (lg[e] > s1) { s1 = lg[e]; i1 = e; }
        int i2 = -1; float s2 = -3.0e38f;
#pragma unroll
        for (int e = 0; e < NE; ++e) if (e != i1 && lg[e] > s2) { s2 = lg[e]; i2 = e; }
        float g1 = 1.f / (1.f + expf(s2 - s1));
        float g2 = 1.f - g1;
        int p1 = atomicAdd(&counts[i1], 1);
        listTok[i1 * T_TOK + p1] = t;
        int p2 = atomicAdd(&counts[i2], 1);
        listTok[i2 * T_TOK + p2] = t;
        tokRec[t]  = make_int4(i1, p1, i2, p2);
        tokGate[t] = make_float2(g1, g2);
    }
}

// ---------------- 256-padded exclusive scan ----------------
__global__ void k_offsets(const int* __restrict__ counts, int* __restrict__ offsets)
{
    int cum = 0;
    for (int e = 0; e < NE; ++e) { offsets[e] = cum; cum += (counts[e] + 255) & ~255; }
    offsets[NE] = cum;
}

// ---------------- weight pack: fp32 [E][K][N] -> bf16 swizzled [E][K/64][N][64] ----------------
// element (e,k,n) -> dst[e][(k>>6)*N + n]*64 + ((g ^ (n&7))*8 + (k&7)], g=(k&63)>>3
__global__ __launch_bounds__(256) void k_packw(const float* __restrict__ src,
                                               unsigned short* __restrict__ dst,
                                               int K, int N)
{
    __shared__ float tile[64][65];
    int e  = blockIdx.z;
    int n0 = blockIdx.x * 64;
    int k0 = blockIdx.y * 64;
    const float* s    = src + (size_t)e * K * N;
    unsigned short* d = dst + (size_t)e * K * N;
    int tid = threadIdx.x;
#pragma unroll
    for (int i = 0; i < 4; ++i) {
        int u  = i * 256 + tid;
        int kk = u >> 4;
        int nn = (u & 15) * 4;
        float4 v = *(const float4*)(s + (size_t)(k0 + kk) * N + n0 + nn);
        tile[kk][nn] = v.x; tile[kk][nn + 1] = v.y; tile[kk][nn + 2] = v.z; tile[kk][nn + 3] = v.w;
    }
    __syncthreads();
#pragma unroll
    for (int i = 0; i < 4; ++i) {
        int u  = i * 256 + tid;
        int nn = u >> 4;
        int g  = (u >> 1) & 7;
        int h  = (u & 1) * 4;
        int kc = g * 8 + h;
        int n  = n0 + nn;
        ushort4 o;
        o.x = f2bf(tile[kc + 0][nn]); o.y = f2bf(tile[kc + 1][nn]);
        o.z = f2bf(tile[kc + 2][nn]); o.w = f2bf(tile[kc + 3][nn]);
        int gp = g ^ (n & 7);
        size_t off = ((size_t)(k0 >> 6) * N + n) * 64 + gp * 8 + h;
        *(ushort4*)(d + off) = o;
    }
}

// ---------------- A pack: gather + bf16 into swizzled [16][PADROWS][64] ----------------
__global__ __launch_bounds__(256) void k_packa(
    const float* __restrict__ x, const int* __restrict__ listTok,
    const int* __restrict__ counts, const int* __restrict__ offsets,
    unsigned short* __restrict__ ap)
{
    int r0  = blockIdx.x * 64;
    int kt  = blockIdx.y;
    int tid = threadIdx.x;
    __shared__ int toks[64];
    if (tid < 64) {
        int r = r0 + tid;
        int tok = 0;
        int total = offsets[NE];
        if (r < total) {
            int e = 0;
#pragma unroll
            for (int j = 1; j < NE; ++j) if (r >= offsets[j]) e = j;
            int local = r - offsets[e];
            int c = counts[e];
            if (local >= c) local = c - 1;
            if (local < 0) local = 0;
            tok = (c > 0) ? listTok[e * T_TOK + local] : 0;
        }
        toks[tid] = tok;
    }
    __syncthreads();
#pragma unroll
    for (int i = 0; i < 4; ++i) {
        int u  = i * 256 + tid;
        int rl = u >> 4;
        int g  = (u >> 1) & 7;
        int h  = (u & 1) * 4;
        int tok = toks[rl];
        float4 v = *(const float4*)(x + (size_t)tok * DM + kt * 64 + g * 8 + h);
        ushort4 o; o.x = f2bf(v.x); o.y = f2bf(v.y); o.z = f2bf(v.z); o.w = f2bf(v.w);
        int row = r0 + rl;
        int gp  = g ^ (row & 7);
        size_t off = ((size_t)kt * PADROWS + row) * 64 + gp * 8 + h;
        *(ushort4*)(ap + off) = o;
    }
}

// ==================== GEMM1: 128x128 tile, BK=64, m97-structure, PERSISTENT work-stealing ====================
// grid = 1280 = 5 blocks/CU (LDS-limited max), each block pulls tiles from a global counter.
// Tile space 8192: w -> y = w>>8 (slow: B-panel/L3 temporal locality), e = (w>>5)&7, mt = w&31.
// Dead tiles (m0 >= cnt) cost one atomic + two barriers instead of a block launch; work
// balances on demand, CUs stay fully resident for the whole kernel.
__global__ __launch_bounds__(256) void k_ffn1(
    const unsigned short* __restrict__ ap, const unsigned short* __restrict__ w1p,
    const float* __restrict__ b1, const int* __restrict__ counts,
    const int* __restrict__ offsets, unsigned short* __restrict__ Hp,
    int* __restrict__ wctr)
{
    __shared__ __align__(16) unsigned short lsA[128 * 64];   // 16 KB
    __shared__ __align__(16) unsigned short lsB[128 * 64];   // 16 KB
    __shared__ int s_w;
    int tid = threadIdx.x, wv = tid >> 6, l = tid & 63;
    int wm = wv & 1, wn = wv >> 1;

    while (true) {
        __syncthreads();   // guards LDS reuse across tiles (drains lgkm/vm of epilogue)
        if (tid == 0) s_w = atomicAdd(wctr, 1);
        __syncthreads();
        int w = s_w;
        if (w >= 8192) break;
        int y  = w >> 8;           // 0..31
        int e  = (w >> 5) & 7;
        int mt = w & 31;
        int cnt = counts[e];
        int m0  = mt << 7;
        if (m0 >= cnt) continue;
        int hbase = offsets[e];
        int n0    = y << 7;

        const unsigned short* srcA = ap + ((size_t)hbase + m0) * 64;
        const unsigned short* srcB = w1p + (size_t)e * DM * DF;

        f32x4 acc[4][4];
#pragma unroll
        for (int a = 0; a < 4; ++a)
#pragma unroll
            for (int b = 0; b < 4; ++b) acc[a][b] = (f32x4)(0.f);

        for (int kt = 0; kt < 16; ++kt) {
            const unsigned short* gA = srcA + (size_t)kt * PADROWS * 64;
            const unsigned short* gB = srcB + ((size_t)kt * DF + n0) * 64;
#pragma unroll
            for (int jj = 0; jj < 4; ++jj) {
                int c = (wv * 4 + jj) * 512;   // 1 KB chunks (elements)
                async_cp16(gA + c + l * 8, lsA + c);
                async_cp16(gB + c + l * 8, lsB + c);
            }
            __syncthreads();
#pragma unroll
            for (int ks = 0; ks < 2; ++ks) {
                short8 aF[4], bF[4];
#pragma unroll
                for (int mi = 0; mi < 4; ++mi) {
                    int row = wm * 64 + mi * 16 + (l & 15);
                    int g   = ks * 4 + (l >> 4);
                    aF[mi] = *(const short8*)&lsA[row * 64 + ((g ^ (row & 7)) << 3)];
                }
#pragma unroll
                for (int ni = 0; ni < 4; ++ni) {
                    int row = wn * 64 + ni * 16 + (l & 15);
                    int g   = ks * 4 + (l >> 4);
                    bF[ni] = *(const short8*)&lsB[row * 64 + ((g ^ (row & 7)) << 3)];
                }
#pragma unroll
                for (int mi = 0; mi < 4; ++mi)
#pragma unroll
                    for (int ni = 0; ni < 4; ++ni)
                        acc[mi][ni] = __builtin_amdgcn_mfma_f32_16x16x32_bf16(aF[mi], bF[ni], acc[mi][ni], 0, 0, 0);
            }
            __syncthreads();
        }

        // epilogue: bias + exact GELU -> LDS packed image -> vectorized store
        int q = l >> 4, cn = l & 15;
#pragma unroll
        for (int mi = 0; mi < 4; ++mi) {
#pragma unroll
            for (int ni = 0; ni < 4; ++ni) {
                int nloc = wn * 64 + ni * 16 + cn;             // 0..127
                float bias = b1[e * DF + n0 + nloc];
                unsigned short* base = (nloc & 64) ? lsB : lsA;
                int kc = nloc & 63, g = kc >> 3;
#pragma unroll
                for (int rg = 0; rg < 4; ++rg) {
                    int m = wm * 64 + mi * 16 + q * 4 + rg;
                    float v = acc[mi][ni][rg] + bias;
                    v = 0.5f * v * (1.f + erff(v * 0.70710678118f));
                    int gp = g ^ (m & 7);
                    base[m * 64 + gp * 8 + (kc & 7)] = f2bf(v);
                }
            }
        }
        __syncthreads();
        {
            int c = tid >> 7;            // slab 0/1
            int r = tid & 127;           // row
            const unsigned short* s = (c ? lsB : lsA) + r * 64;
            unsigned short* dst = Hp + (((size_t)(n0 >> 6) + c) * PADROWS + hbase + m0 + r) * 64;
#pragma unroll
            for (int jj = 0; jj < 8; ++jj)
                *(ushort8_t*)(dst + jj * 8) = *(const ushort8_t*)(s + jj * 8);
        }
    }
}

// ==================== GEMM2: 128x128 tile, BK=64, K=4096, PERSISTENT work-stealing, plain store ====================
// Tile space 2048: w -> y = w>>8 (0..7), e = (w>>5)&7, mt = w&31.
__global__ __launch_bounds__(256) void k_ffn2(
    const unsigned short* __restrict__ Hp, const unsigned short* __restrict__ w2p,
    const float* __restrict__ b2, const int* __restrict__ counts,
    const int* __restrict__ offsets, float* __restrict__ ypart,
    int* __restrict__ wctr)
{
    __shared__ __align__(16) unsigned short lsA[128 * 64];
    __shared__ __align__(16) unsigned short lsB[128 * 64];
    __shared__ int s_w;
    int tid = threadIdx.x, wv = tid >> 6, l = tid & 63;
    int wm = wv & 1, wn = wv >> 1;

    while (true) {
        __syncthreads();
        if (tid == 0) s_w = atomicAdd(wctr, 1);
        __syncthreads();
        int w = s_w;
        if (w >= 2048) break;
        int y  = w >> 8;           // 0..7
        int e  = (w >> 5) & 7;
        int mt = w & 31;
        int cnt = counts[e];
        int m0  = mt << 7;
        if (m0 >= cnt) continue;
        int R0 = offsets[e] + m0;
        int n0 = y << 7;

        const unsigned short* srcA = Hp + (size_t)R0 * 64;
        const unsigned short* srcB = w2p + (size_t)e * DF * DM;

        f32x4 acc[4][4];
#pragma unroll
        for (int a = 0; a < 4; ++a)
#pragma unroll
            for (int b = 0; b < 4; ++b) acc[a][b] = (f32x4)(0.f);

        for (int kt = 0; kt < 64; ++kt) {
            const unsigned short* gA = srcA + (size_t)kt * PADROWS * 64;
            const unsigned short* gB = srcB + ((size_t)kt * DM + n0) * 64;
#pragma unroll
            for (int jj = 0; jj < 4; ++jj) {
                int c = (wv * 4 + jj) * 512;
                async_cp16(gA + c + l * 8, lsA + c);
                async_cp16(gB + c + l * 8, lsB + c);
            }
            __syncthreads();
#pragma unroll
            for (int ks = 0; ks < 2; ++ks) {
                short8 aF[4], bF[4];
#pragma unroll
                for (int mi = 0; mi < 4; ++mi) {
                    int row = wm * 64 + mi * 16 + (l & 15);
                    int g   = ks * 4 + (l >> 4);
                    aF[mi] = *(const short8*)&lsA[row * 64 + ((g ^ (row & 7)) << 3)];
                }
#pragma unroll
                for (int ni = 0; ni < 4; ++ni) {
                    int row = wn * 64 + ni * 16 + (l & 15);
                    int g   = ks * 4 + (l >> 4);
                    bF[ni] = *(const short8*)&lsB[row * 64 + ((g ^ (row & 7)) << 3)];
                }
#pragma unroll
                for (int mi = 0; mi < 4; ++mi)
#pragma unroll
                    for (int ni = 0; ni < 4; ++ni)
                        acc[mi][ni] = __builtin_amdgcn_mfma_f32_16x16x32_bf16(aF[mi], bF[ni], acc[mi][ni], 0, 0, 0);
            }
            __syncthreads();
        }

        // epilogue: + b2, plain fp32 store (no atomics); padded rows are dead
        int q = l >> 4, cn = l & 15;
        float bias[4];
#pragma unroll
        for (int ni = 0; ni < 4; ++ni) bias[ni] = b2[e * DM + n0 + wn * 64 + ni * 16 + cn];
#pragma unroll
        for (int mi = 0; mi < 4; ++mi) {
#pragma unroll
            for (int rg = 0; rg < 4; ++rg) {
                int m = wm * 64 + mi * 16 + q * 4 + rg;
                float* orow = ypart + ((size_t)R0 + m) * DM;
#pragma unroll
                for (int ni = 0; ni < 4; ++ni)
                    orow[n0 + wn * 64 + ni * 16 + cn] = acc[mi][ni][rg] + bias[ni];
            }
        }
    }
}

// ---------------- gather: out[t] = g1*ypart[r1] + g2*ypart[r2] ----------------
__global__ __launch_bounds__(256) void k_gather(
    const float* __restrict__ yp, const int4* __restrict__ rec,
    const float2* __restrict__ gg, const int* __restrict__ offsets,
    float* __restrict__ out)
{
    int t = blockIdx.x;
    int4 rc = rec[t];
    float2 w = gg[t];
    size_t r1 = (size_t)offsets[rc.x] + rc.y;
    size_t r2 = (size_t)offsets[rc.z] + rc.w;
    const float4* a = (const float4*)(yp + r1 * DM);
    const float4* b = (const float4*)(yp + r2 * DM);
    float4 va = a[threadIdx.x], vb = b[threadIdx.x];
    float4 o;
    o.x = w.x * va.x + w.y * vb.x;
    o.y = w.x * va.y + w.y * vb.y;
    o.z = w.x * va.z + w.y * vb.z;
    o.w = w.x * va.w + w.y * vb.w;
    ((float4*)(out + (size_t)t * DM))[threadIdx.x] = o;
}

extern "C" void kernel_launch(void* const* d_in, const int* in_sizes, int n_in,
                              void* d_out, int out_size, void* d_ws, size_t ws_size,
                              hipStream_t stream)
{
    const float* x  = (const float*)d_in[0];
    const float* rw = (const float*)d_in[1];
    const float* rb = (const float*)d_in[2];
    const float* w1 = (const float*)d_in[3];
    const float* b1 = (const float*)d_in[4];
    const float* w2 = (const float*)d_in[5];
    const float* b2 = (const float*)d_in[6];
    float* out = (float*)d_out;

    char* ws = (char*)d_ws;
    // workspace layout — footprint 214,270,464 B (proven).
    // w2p ALIASES apack+w1p region: written by 2nd k_packw AFTER k_ffn1 consumed both.
    int*            counts   = (int*)(ws + 0);      // 32 B
    int*            wctr1    = (int*)(ws + 64);     // ffn1 work counter
    int*            wctr2    = (int*)(ws + 68);     // ffn2 work counter
    int*            offsets  = (int*)(ws + 128);
    int*            listTok  = (int*)(ws + 512);
    unsigned short* apack    = (unsigned short*)(ws + 262656);     // 21.0 MB [16][10240][64]
    unsigned short* w2p      = (unsigned short*)(ws + 262656);     // 64 MB (alias, after ffn1)
    unsigned short* w1p      = (unsigned short*)(ws + 21234176);   // 64 MB
    unsigned short* Hp       = (unsigned short*)(ws + 88343040);   // 83.9 MB [64][10240][64]
    float*          ypart    = (float*)(ws + 172229120);           // 41.9 MB [10240][1024]
    int4*           tokRec   = (int4*)(ws + 214172160);            // 64 KB
    float2*         tokGate  = (float2*)(ws + 214237696);          // 32 KB

    hipMemsetAsync(ws, 0, 128, stream);   // counts + work counters

    k_router <<<T_TOK / 4, 256, 0, stream>>>(x, rw, rb, counts, listTok, tokRec, tokGate);
    k_offsets<<<1, 1, 0, stream>>>(counts, offsets);
    k_packw  <<<dim3(DF / 64, DM / 64, NE), 256, 0, stream>>>(w1, w1p, DM, DF);
    k_packa  <<<dim3(PADROWS / 64, 16), 256, 0, stream>>>(x, listTok, counts, offsets, apack);
    k_ffn1   <<<1280, 256, 0, stream>>>(apack, w1p, b1, counts, offsets, Hp, wctr1);
    k_packw  <<<dim3(DM / 64, DF / 64, NE), 256, 0, stream>>>(w2, w2p, DF, DM);
    k_ffn2   <<<1280, 256, 0, stream>>>(Hp, w2p, b2, counts, offsets, ypart, wctr2);
    k_gather <<<T_TOK, 256, 0, stream>>>(ypart, tokRec, tokGate, offsets, out);
}